// Round 1
// 200.169 us; speedup vs baseline: 1.0212x; 1.0212x over previous
//
#include <hip/hip_runtime.h>
#include <math.h>

// Problem constants: N=2, C_out=64, C_in=3, H=256, Wf=129, irfft2 to 256x256
#define H_   256
#define Wf_  129
#define HWf_ 33024      // 256*129
#define CIN_ 3
#define COUT_ 64
#define TW_  0.0245436926f   // 2*pi/256

typedef float f32x4 __attribute__((ext_vector_type(4)));  // builtin-compatible

// ---------------------------------------------------------------------------
// Stage 1: Xhat[n,ci,hw] = X[ci] + (1/64) * sum_co D[ci]*(Y/a - num/den)
//   num = Y*sum|D|^2 + a*sum(conj(D)*X),  den = a*sum|D|^2 + a^2,  a=alpha/3
// Each thread: one PAIR of consecutive hw positions (16B loads), 4 co.
// Block 256 = 16 pairs x 16 co-groups; LDS-reduce 16 partials.
// Grid 2064 blocks (8.06/CU). D/Y are zero-reuse -> nontemporal loads.
// NEW: output written TRANSPOSED as [n,ci,w,h] (h contiguous) so stage2
// reads coalesced. Epilogue stores were scattered anyway -> zero cost.
// ---------------------------------------------------------------------------
__global__ __launch_bounds__(256) void solve_stage1(
    const float* __restrict__ X, const float* __restrict__ D,
    const float* __restrict__ Y, const float* __restrict__ alpha,
    float* __restrict__ Xhat)
{
    const int tid  = threadIdx.x;
    const int pl   = tid & 15;              // pair lane 0..15
    const int cog  = tid >> 4;              // co-group 0..15
    const int pair = blockIdx.x * 16 + pl;
    const int pos0 = pair * 2;              // global complex position
    const int n    = pos0 / HWf_;           // uniform per block (1032 blocks/n)
    const int hw0  = pos0 - n * HWf_;

    const float a    = alpha[n] * (1.0f / 3.0f);
    const float inva = 1.0f / a;
    const float a2   = a * a;

    f32x4 x[3];
#pragma unroll
    for (int ci = 0; ci < 3; ++ci)
        x[ci] = *(const f32x4*)(X + ((size_t)(n * 3 + ci) * HWf_ + hw0) * 2);

    const int co0 = cog * 4;
    const float* Dp = D + ((size_t)(n * 64 + co0) * 3) * (HWf_ * 2) + hw0 * 2;
    const float* Yp = Y + ((size_t)(n * 64 + co0)) * (HWf_ * 2) + hw0 * 2;

    // acc layout: q = pos*6 + ci*2 + (0=re,1=im)
    float acc[12];
#pragma unroll
    for (int q = 0; q < 12; ++q) acc[q] = 0.f;

#pragma unroll
    for (int co = 0; co < 4; ++co) {
        f32x4 y  = __builtin_nontemporal_load(
                       (const f32x4*)(Yp + (size_t)co * (HWf_ * 2)));
        f32x4 d0 = __builtin_nontemporal_load(
                       (const f32x4*)(Dp + (size_t)(co * 3 + 0) * (HWf_ * 2)));
        f32x4 d1 = __builtin_nontemporal_load(
                       (const f32x4*)(Dp + (size_t)(co * 3 + 1) * (HWf_ * 2)));
        f32x4 d2 = __builtin_nontemporal_load(
                       (const f32x4*)(Dp + (size_t)(co * 3 + 2) * (HWf_ * 2)));

        // position 0 (components 0=re,1=im)
        {
            float s2 = d0[0]*d0[0] + d0[1]*d0[1] + d1[0]*d1[0] + d1[1]*d1[1]
                     + d2[0]*d2[0] + d2[1]*d2[1];
            float sr = d0[0]*x[0][0] + d0[1]*x[0][1] + d1[0]*x[1][0] + d1[1]*x[1][1]
                     + d2[0]*x[2][0] + d2[1]*x[2][1];
            float si = d0[0]*x[0][1] - d0[1]*x[0][0] + d1[0]*x[1][1] - d1[1]*x[1][0]
                     + d2[0]*x[2][1] - d2[1]*x[2][0];
            float nr = y[0] * s2 + a * sr, ni = y[1] * s2 + a * si;
            float invden = 1.0f / (a * s2 + a2);
            float tr = y[0] * inva - nr * invden;
            float ti = y[1] * inva - ni * invden;
            acc[0] += d0[0]*tr - d0[1]*ti;  acc[1] += d0[0]*ti + d0[1]*tr;
            acc[2] += d1[0]*tr - d1[1]*ti;  acc[3] += d1[0]*ti + d1[1]*tr;
            acc[4] += d2[0]*tr - d2[1]*ti;  acc[5] += d2[0]*ti + d2[1]*tr;
        }
        // position 1 (components 2=re,3=im)
        {
            float s2 = d0[2]*d0[2] + d0[3]*d0[3] + d1[2]*d1[2] + d1[3]*d1[3]
                     + d2[2]*d2[2] + d2[3]*d2[3];
            float sr = d0[2]*x[0][2] + d0[3]*x[0][3] + d1[2]*x[1][2] + d1[3]*x[1][3]
                     + d2[2]*x[2][2] + d2[3]*x[2][3];
            float si = d0[2]*x[0][3] - d0[3]*x[0][2] + d1[2]*x[1][3] - d1[3]*x[1][2]
                     + d2[2]*x[2][3] - d2[3]*x[2][2];
            float nr = y[2] * s2 + a * sr, ni = y[3] * s2 + a * si;
            float invden = 1.0f / (a * s2 + a2);
            float tr = y[2] * inva - nr * invden;
            float ti = y[3] * inva - ni * invden;
            acc[6]  += d0[2]*tr - d0[3]*ti;  acc[7]  += d0[2]*ti + d0[3]*tr;
            acc[8]  += d1[2]*tr - d1[3]*ti;  acc[9]  += d1[2]*ti + d1[3]*tr;
            acc[10] += d2[2]*tr - d2[3]*ti;  acc[11] += d2[2]*ti + d2[3]*tr;
        }
    }

    __shared__ float red[16 * 192];   // [cog][pair][q] = 12 KB
    {
        const int base = cog * 192 + pl * 12;
#pragma unroll
        for (int q = 0; q < 12; ++q) red[base + q] = acc[q];
    }
    __syncthreads();

    if (tid < 192) {
        float s = 0.f;
#pragma unroll
        for (int c = 0; c < 16; ++c) s += red[c * 192 + tid];
        const int P   = tid / 12;
        const int r   = tid - P * 12;
        const int pos = r / 6;
        const int rr  = r - pos * 6;
        const int ci  = rr >> 1;
        const int cc  = rr & 1;
        const int gp  = (blockIdx.x * 16 + P) * 2 + pos;
        const int hw  = gp - n * HWf_;
        const int h   = hw / Wf_;
        const int w   = hw - h * Wf_;
        const size_t so = ((size_t)(n * 3 + ci) * HWf_ + hw) * 2 + cc;
        // transposed: [n,ci,w,h]
        const size_t o = (((size_t)(n * 3 + ci) * Wf_ + w) * H_ + h) * 2 + cc;
        Xhat[o] = X[so] + s * (1.0f / 64.0f);
    }
}

// ---------------------------------------------------------------------------
// Stage 2: inverse complex DFT along h (length 256, 1/256 norm).
//   out[h] = (1/256) sum_k in[k] e^{+i 2pi k h/256}
// Input/output layout: [n_ci*Wf][H] (h contiguous) -> fully coalesced loads
// and stores. Block = 256 threads = 2 columns x 128; thread t computes h=t
// and h=t+128 (twiddle differs by (-1)^k). Twiddle via register recurrence,
// exact refresh every 32 steps from integer-reduced argument.
// ---------------------------------------------------------------------------
__global__ __launch_bounds__(256) void solve_stage2(
    const float2* __restrict__ in, float2* __restrict__ out)
{
    __shared__ float2 col[2][256];

    const int b   = blockIdx.x;         // column pair, 387 blocks
    const int sub = threadIdx.x >> 7;   // which column of the pair
    const int t   = threadIdx.x & 127;  // 0..127

    const float2* src = in + ((size_t)b * 2 + sub) * H_;
    col[sub][t]       = src[t];
    col[sub][t + 128] = src[t + 128];
    __syncthreads();

    float wc, wsn;
    sincosf((float)t * TW_, &wsn, &wc);   // step multiplier e^{i*2pi*t/256}

    float ar = 0.f, ai = 0.f, br = 0.f, bi = 0.f;
    for (int kb = 0; kb < 8; ++kb) {
        const int k0 = kb * 32;
        float tr, ti;
        {
            const int m = (t * k0) & 255;     // exact integer phase reduction
            float s, c; sincosf((float)m * TW_, &s, &c);
            tr = c; ti = s;
        }
#pragma unroll
        for (int j = 0; j < 32; ++j) {
            const float2 v = col[sub][k0 + j];  // broadcast within wave
            const float pr = v.x * tr - v.y * ti;
            const float pi = v.x * ti + v.y * tr;
            ar += pr; ai += pi;
            if ((k0 + j) & 1) { br -= pr; bi -= pi; }
            else             { br += pr; bi += pi; }
            const float nt = tr * wc - ti * wsn;
            ti = tr * wsn + ti * wc;
            tr = nt;
        }
    }

    float2* dst = out + ((size_t)b * 2 + sub) * H_;
    dst[t]       = make_float2(ar * (1.0f / 256.0f), ai * (1.0f / 256.0f));
    dst[t + 128] = make_float2(br * (1.0f / 256.0f), bi * (1.0f / 256.0f));
}

// ---------------------------------------------------------------------------
// Stage 3: c2r inverse DFT along w (n=256 from 129 bins, 1/256 norm),
// numpy semantics (imag of bins 0 and 128 ignored):
//   x[m] = (1/256)[X0.re + (-1)^m X128.re + 2 sum_{k=1}^{127}(Xr cos - Xi sin)]
// Input layout now [n_ci*Wf][H]: gather 129 bins at stride H (2 KB) per row;
// data is L2/L3-resident (stage2 just wrote 3.2 MB). Output coalesced.
// Block = 128 threads, one row; thread t computes m=t and m=t+128.
// ---------------------------------------------------------------------------
__global__ __launch_bounds__(128) void solve_stage3(
    const float2* __restrict__ in, float* __restrict__ out)
{
    __shared__ float2 row[Wf_];

    const int b    = blockIdx.x;        // n_ci*256 + h, 1536 blocks
    const int n_ci = b >> 8;
    const int h    = b & 255;
    const int t    = threadIdx.x;       // 0..127

    row[t] = in[((size_t)n_ci * Wf_ + t) * H_ + h];
    if (t == 0) row[128] = in[((size_t)n_ci * Wf_ + 128) * H_ + h];
    __syncthreads();

    float wc, wsn;
    sincosf((float)t * TW_, &wsn, &wc);

    float sa = 0.f, sb = 0.f;           // sums over k=0..127 for m=t, m=t+128
    for (int kb = 0; kb < 4; ++kb) {
        const int k0 = kb * 32;
        float tr, ti;
        {
            const int m = (t * k0) & 255;
            float s, c; sincosf((float)m * TW_, &s, &c);
            tr = c; ti = s;
        }
#pragma unroll
        for (int j = 0; j < 32; ++j) {
            const float2 v = row[k0 + j];     // broadcast
            const float pr = v.x * tr - v.y * ti;   // Re(X_k e^{+i th})
            sa += pr;
            if ((k0 + j) & 1) sb -= pr; else sb += pr;
            const float nt = tr * wc - ti * wsn;
            ti = tr * wsn + ti * wc;
            tr = nt;
        }
    }

    const float sgn  = (t & 1) ? -1.0f : 1.0f;     // (-1)^m, same for m and m+128
    const float base = -0.5f * row[0].x + sgn * 0.5f * row[128].x;
    __builtin_nontemporal_store((sa + base) * (1.0f / 128.0f),
                                out + (size_t)b * 256 + t);
    __builtin_nontemporal_store((sb + base) * (1.0f / 128.0f),
                                out + (size_t)b * 256 + t + 128);
}

// ---------------------------------------------------------------------------
extern "C" void kernel_launch(void* const* d_in, const int* in_sizes, int n_in,
                              void* d_out, int out_size, void* d_ws, size_t ws_size,
                              hipStream_t stream) {
    const float* X     = (const float*)d_in[0];  // (2,1,3,256,129,2)
    const float* D     = (const float*)d_in[1];  // (2,64,3,256,129,2)
    const float* Y     = (const float*)d_in[2];  // (2,64,1,256,129,2)
    const float* alpha = (const float*)d_in[3];  // (2,)
    // d_in[4] = x_size (int64[2]) -- hardcoded 256x256

    float* ws1 = (float*)d_ws;                       // Xhat^T: 6*129*256 cplx
    float2* ws2 = (float2*)(ws1 + (size_t)CIN_ * 2 * HWf_ * 2);

    solve_stage1<<<2064, 256, 0, stream>>>(X, D, Y, alpha, ws1);
    solve_stage2<<<(2 * CIN_ * Wf_) / 2, 256, 0, stream>>>((const float2*)ws1, ws2);
    solve_stage3<<<2 * CIN_ * H_, 128, 0, stream>>>(ws2, (float*)d_out);
}